// Round 1
// baseline (431.820 us; speedup 1.0000x reference)
//
#include <hip/hip_runtime.h>

// LSTM discriminator: B=2048, T=1024, I=4, H=16, gates 4H=64.
// Layout: 1 wave (64 threads) per block = 2 sequences (32 lanes each).
// Lane l (in half): owns gate rows r1=l and r2=l+32 of W_hh/W_ih.
//   l<16   : r1 = i-row l,  r2 = g-row l+32  (act1=sigmoid, act2=tanh)
//   l>=16  : r1 = f-row l,  r2 = o-row l+32  (act1=sigmoid, act2=sigmoid)
// h broadcast per timestep via double-buffered LDS (write 1 f32, read 4 float4).
// c lives in a register at lanes l<16. Readout: width-16 shfl_xor reduce.

#define T_DIM 1024
#define LOG2E 1.4426950408889634f

__device__ __forceinline__ float fsig(float x) {
    // sigmoid(x) = 1 / (1 + 2^(-x*log2e)); hw exp2 + hw rcp (~1 ulp each)
    float e = __builtin_amdgcn_exp2f(-x * LOG2E);
    return __builtin_amdgcn_rcpf(1.0f + e);
}

__global__ __launch_bounds__(64) void lstm_disc_kernel(
    const float* __restrict__ x,      // [B, T, 4]
    const float* __restrict__ W_ih,   // [64, 4]
    const float* __restrict__ W_hh,   // [64, 16]
    const float* __restrict__ b_ih,   // [64]
    const float* __restrict__ b_hh,   // [64]
    const float* __restrict__ W_d,    // [1, 16]
    const float* __restrict__ b_d,    // [1]
    float* __restrict__ out)          // [B, T]
{
    const int tid  = threadIdx.x;        // 0..63
    const int half = tid >> 5;           // which sequence in this wave
    const int l    = tid & 31;           // lane within sequence
    const int j    = l & 15;             // hidden index
    const bool low = (l < 16);
    const int batch = blockIdx.x * 2 + half;

    const int r1 = l;                    // i-row (low) or f-row (high)
    const int r2 = l + 32;               // g-row (low) or o-row (high)

    // ---- per-lane persistent weights (registers) ----
    float W1[16], W2[16];
    {
        const float4* w1p = reinterpret_cast<const float4*>(W_hh + r1 * 16);
        const float4* w2p = reinterpret_cast<const float4*>(W_hh + r2 * 16);
#pragma unroll
        for (int q = 0; q < 4; ++q) {
            float4 a = w1p[q], b = w2p[q];
            W1[q*4+0] = a.x; W1[q*4+1] = a.y; W1[q*4+2] = a.z; W1[q*4+3] = a.w;
            W2[q*4+0] = b.x; W2[q*4+1] = b.y; W2[q*4+2] = b.z; W2[q*4+3] = b.w;
        }
    }
    const float4 Wx1 = *reinterpret_cast<const float4*>(W_ih + r1 * 4);
    const float4 Wx2 = *reinterpret_cast<const float4*>(W_ih + r2 * 4);
    const float bias1 = b_ih[r1] + b_hh[r1];
    const float bias2 = b_ih[r2] + b_hh[r2];
    const float wd = low ? W_d[j] : 0.0f;   // readout weight (0 on junk lanes)
    const float bd = b_d[0];
    const float m2 = low ? 2.0f : 1.0f;     // act2: tanh = 2*sig(2x)-1 ; sigmoid = 1*sig(1x)-0
    // shfl partner: low lanes fetch (f, o) from lane+16; high lanes read self (harmless)
    const int partner = (tid & 32) | (16 + j);

    __shared__ __align__(16) float h_lds[2][2][16];   // [buf][half][hidden]
    if (low) h_lds[0][half][j] = 0.0f;                // h_0 = 0
    __syncthreads();

    float c = 0.0f;
    const float* xb = x + (size_t)batch * (T_DIM * 4);
    float4 xv = *reinterpret_cast<const float4*>(xb); // x_0 (all lanes same addr -> broadcast)

    float ob0 = 0.f, ob1 = 0.f, ob2 = 0.f, ob3 = 0.f;

    for (int t4 = 0; t4 < T_DIM; t4 += 4) {
#pragma unroll
        for (int u = 0; u < 4; ++u) {
            const int t = t4 + u;
            // prefetch next x (clamped: last load re-reads final element, stays in-bounds)
            const int tn = (t + 1 < T_DIM) ? (t + 1) : (T_DIM - 1);
            float4 xn = *reinterpret_cast<const float4*>(xb + tn * 4);

            __syncthreads();  // make prev iteration's h-write visible (1-wave block: cheap)

            // broadcast h_t (16 floats) from LDS; buffer parity is compile-time (t4 % 2 == 0)
            const float4* hp = reinterpret_cast<const float4*>(&h_lds[u & 1][half][0]);
            float4 h0 = hp[0], h1 = hp[1], h2 = hp[2], h3 = hp[3];

            // gate pre-activations: bias + x-proj + h-dot (split accumulators for ILP)
            float b1 = fmaf(Wx1.x, xv.x, fmaf(Wx1.y, xv.y, fmaf(Wx1.z, xv.z, fmaf(Wx1.w, xv.w, bias1))));
            float b2 = fmaf(Wx2.x, xv.x, fmaf(Wx2.y, xv.y, fmaf(Wx2.z, xv.z, fmaf(Wx2.w, xv.w, bias2))));

            float a1 = fmaf(W1[ 0], h0.x, fmaf(W1[ 1], h0.y, fmaf(W1[ 2], h0.z, fmaf(W1[ 3], h0.w, b1))));
            float a2 = fmaf(W1[ 4], h1.x, fmaf(W1[ 5], h1.y, fmaf(W1[ 6], h1.z, W1[ 7] * h1.w)));
            float a3 = fmaf(W1[ 8], h2.x, fmaf(W1[ 9], h2.y, fmaf(W1[10], h2.z, W1[11] * h2.w)));
            float a4 = fmaf(W1[12], h3.x, fmaf(W1[13], h3.y, fmaf(W1[14], h3.z, W1[15] * h3.w)));
            float g1 = (a1 + a2) + (a3 + a4);

            float c1 = fmaf(W2[ 0], h0.x, fmaf(W2[ 1], h0.y, fmaf(W2[ 2], h0.z, fmaf(W2[ 3], h0.w, b2))));
            float c2 = fmaf(W2[ 4], h1.x, fmaf(W2[ 5], h1.y, fmaf(W2[ 6], h1.z, W2[ 7] * h1.w)));
            float c3 = fmaf(W2[ 8], h2.x, fmaf(W2[ 9], h2.y, fmaf(W2[10], h2.z, W2[11] * h2.w)));
            float c4 = fmaf(W2[12], h3.x, fmaf(W2[13], h3.y, fmaf(W2[14], h3.z, W2[15] * h3.w)));
            float g2 = (c1 + c2) + (c3 + c4);

            // activations (branch-free): act1 = sigmoid(g1); act2 = m2*sigmoid(m2*g2) - (m2-1)
            float act1 = fsig(g1);
            float act2 = fmaf(m2, fsig(m2 * g2), -(m2 - 1.0f));

            // gather f,o from partner lane; update c,h (valid at l<16)
            float sf = __shfl(act1, partner, 64);
            float so = __shfl(act2, partner, 64);
            c = fmaf(sf, c, act1 * act2);                       // c = f*c + i*g
            float tc = fmaf(2.0f, fsig(2.0f * c), -1.0f);       // tanh(c)
            float h  = so * tc;                                 // h = o * tanh(c)

            // publish h_{t+1} to the other LDS buffer
            if (low) h_lds[(u + 1) & 1][half][j] = h;

            // readout: p = sum_j h_j * W_d[j]  (width-16 butterfly; wd=0 kills junk lanes)
            float p = h * wd;
            p += __shfl_xor(p, 1, 64);
            p += __shfl_xor(p, 2, 64);
            p += __shfl_xor(p, 4, 64);
            p += __shfl_xor(p, 8, 64);
            float o = fsig(p + bd);
            if (u == 0) ob0 = o;
            if (u == 1) ob1 = o;
            if (u == 2) ob2 = o;
            if (u == 3) ob3 = o;

            xv = xn;
        }
        // coalesce 4 timesteps into one 16B store (lane 0 of each sequence)
        if ((tid & 31) == 0) {
            *reinterpret_cast<float4*>(out + (size_t)batch * T_DIM + t4) =
                make_float4(ob0, ob1, ob2, ob3);
        }
    }
}

extern "C" void kernel_launch(void* const* d_in, const int* in_sizes, int n_in,
                              void* d_out, int out_size, void* d_ws, size_t ws_size,
                              hipStream_t stream) {
    const float* x    = (const float*)d_in[0];
    const float* W_ih = (const float*)d_in[1];
    const float* W_hh = (const float*)d_in[2];
    const float* b_ih = (const float*)d_in[3];
    const float* b_hh = (const float*)d_in[4];
    const float* W_d  = (const float*)d_in[5];
    const float* b_d  = (const float*)d_in[6];
    float* out = (float*)d_out;

    // 2048 sequences / 2 per wave-block = 1024 blocks -> 1 wave/SIMD machine-wide
    lstm_disc_kernel<<<1024, 64, 0, stream>>>(x, W_ih, W_hh, b_ih, b_hh, W_d, b_d, out);
}

// Round 3
// 339.938 us; speedup vs baseline: 1.2703x; 1.2703x over previous
//
#include <hip/hip_runtime.h>

// LSTM discriminator: B=2048, T=1024, I=4, H=16, gates 4H=64.
// 1 wave per block = 2 sequences (32 lanes each). Lane s (in half):
//   rows r1=s (i_j low / f_j high), r2=s+32 (g_j low / o_j high), j=s&15.
// No LDS, no barriers. h broadcast = rolling-XOR via DPP (quad_perm +
// row_mirror + row_half_mirror compose to all 16 xor patterns within each
// 16-lane row). Weights pre-permuted per lane: Wp[k] = W[row][j^k], so the
// dot  sum_k Wp[k]*h_{j^k} = full row dot with static register indexing.
// Readout dot folded into the same broadcast (out is one step delayed).
// Gate exchange i/f,g/o: 2 independent ds_swizzle xor16 (only DS ops left).

#define T_DIM 1024
#define LOG2E 1.4426950408889634f

__device__ __forceinline__ float fsig(float x) {
    float e = __builtin_amdgcn_exp2f(-x * LOG2E);
    return __builtin_amdgcn_rcpf(1.0f + e);
}

template<int CTRL>
__device__ __forceinline__ float dpp_f(float v) {
    int i = __float_as_int(v);
    return __int_as_float(__builtin_amdgcn_update_dpp(i, i, CTRL, 0xF, 0xF, false));
}
// DPP ctrl: quad_perm xor1=0xB1 [1,0,3,2], xor2=0x4E [2,3,0,1], xor3=0x1B [3,2,1,0]
//           ROW_MIRROR=0x140 (j^15), ROW_HALF_MIRROR=0x141 (j^7)

__device__ __forceinline__ float swz16(float v) {
    // ds_swizzle BitMode xor=16, and=0x1F: lane j <-> j^16 within each 32-half
    return __int_as_float(__builtin_amdgcn_ds_swizzle(__float_as_int(v), 0x401F));
}

__global__ __launch_bounds__(64) void lstm_disc_kernel(
    const float* __restrict__ x,      // [B, T, 4]
    const float* __restrict__ W_ih,   // [64, 4]
    const float* __restrict__ W_hh,   // [64, 16]
    const float* __restrict__ b_ih,   // [64]
    const float* __restrict__ b_hh,   // [64]
    const float* __restrict__ W_d,    // [1, 16]
    const float* __restrict__ b_d,    // [1]
    float* __restrict__ out)          // [B, T]
{
    const int tid  = threadIdx.x;
    const int half = tid >> 5;
    const int s    = tid & 31;
    const int j    = s & 15;
    const int hi   = (s >> 4) & 1;       // 0: i/g rows, 1: f/o rows
    const int batch = blockIdx.x * 2 + half;
    const int r1 = s, r2 = s + 32;

    // Pre-permuted weights: index k pairs with broadcast value h_{j^k}
    float W1p[16], W2p[16], Wdp[16];
#pragma unroll
    for (int k = 0; k < 16; ++k) {
        const int jx = j ^ k;
        W1p[k] = W_hh[r1 * 16 + jx];
        W2p[k] = W_hh[r2 * 16 + jx];
        Wdp[k] = W_d[jx];
    }
    const float4 Wx1 = *reinterpret_cast<const float4*>(W_ih + r1 * 4);
    const float4 Wx2 = *reinterpret_cast<const float4*>(W_ih + r2 * 4);
    const float bias1 = b_ih[r1] + b_hh[r1];
    const float bias2 = b_ih[r2] + b_hh[r2];
    const float bd = b_d[0];
    const float m2  = hi ? 1.0f : 2.0f;   // act2: tanh (low, m=2) / sigmoid (high, m=1)
    const float m2c = m2 - 1.0f;

    const float4* xp = reinterpret_cast<const float4*>(x + (size_t)batch * (T_DIM * 4));
    float4 xv = xp[0];

    float h = 0.0f, c = 0.0f;
    float s0 = 0.f, s1 = 0.f, s2 = 0.f, s3 = 0.f;

    for (int t4 = 0; t4 < T_DIM; t4 += 4) {
#pragma unroll
        for (int u = 0; u < 4; ++u) {
            const int t = t4 + u;
            const float4 xn = xp[(t + 1 < T_DIM) ? (t + 1) : (T_DIM - 1)];

            // ---- rolling-XOR broadcast of h + three dots (A=row r1, B=row r2, P=readout) ----
            float A0 = W1p[0] * h, B0 = W2p[0] * h, P0 = Wdp[0] * h;
            float A1 = 0.f, B1 = 0.f, P1 = 0.f;

            const float v1 = dpp_f<0xB1>(h);          // j^1
            const float v2 = dpp_f<0x4E>(h);          // j^2
            const float v3 = dpp_f<0x1B>(h);          // j^3
            const float m7 = dpp_f<0x141>(h);         // j^7
            const float mF = dpp_f<0x140>(h);         // j^15
            A1 = fmaf(W1p[1], v1, A1); B1 = fmaf(W2p[1], v1, B1); P1 = fmaf(Wdp[1], v1, P1);
            A0 = fmaf(W1p[2], v2, A0); B0 = fmaf(W2p[2], v2, B0); P0 = fmaf(Wdp[2], v2, P0);
            A1 = fmaf(W1p[3], v3, A1); B1 = fmaf(W2p[3], v3, B1); P1 = fmaf(Wdp[3], v3, P1);
            const float v6 = dpp_f<0xB1>(m7);         // j^6
            const float v5 = dpp_f<0x4E>(m7);         // j^5
            const float v4 = dpp_f<0x1B>(m7);         // j^4
            const float m8 = dpp_f<0x141>(mF);        // j^8
            A0 = fmaf(W1p[7], m7, A0); B0 = fmaf(W2p[7], m7, B0); P0 = fmaf(Wdp[7], m7, P0);
            A1 = fmaf(W1p[6], v6, A1); B1 = fmaf(W2p[6], v6, B1); P1 = fmaf(Wdp[6], v6, P1);
            A0 = fmaf(W1p[5], v5, A0); B0 = fmaf(W2p[5], v5, B0); P0 = fmaf(Wdp[5], v5, P0);
            A1 = fmaf(W1p[4], v4, A1); B1 = fmaf(W2p[4], v4, B1); P1 = fmaf(Wdp[4], v4, P1);
            const float vE = dpp_f<0xB1>(mF);         // j^14
            const float vD = dpp_f<0x4E>(mF);         // j^13
            const float vC = dpp_f<0x1B>(mF);         // j^12
            A0 = fmaf(W1p[15], mF, A0); B0 = fmaf(W2p[15], mF, B0); P0 = fmaf(Wdp[15], mF, P0);
            A1 = fmaf(W1p[14], vE, A1); B1 = fmaf(W2p[14], vE, B1); P1 = fmaf(Wdp[14], vE, P1);
            A0 = fmaf(W1p[13], vD, A0); B0 = fmaf(W2p[13], vD, B0); P0 = fmaf(Wdp[13], vD, P0);
            A1 = fmaf(W1p[12], vC, A1); B1 = fmaf(W2p[12], vC, B1); P1 = fmaf(Wdp[12], vC, P1);
            const float v9 = dpp_f<0xB1>(m8);         // j^9
            const float vA = dpp_f<0x4E>(m8);         // j^10
            const float vB = dpp_f<0x1B>(m8);         // j^11
            A0 = fmaf(W1p[8],  m8, A0); B0 = fmaf(W2p[8],  m8, B0); P0 = fmaf(Wdp[8],  m8, P0);
            A1 = fmaf(W1p[9],  v9, A1); B1 = fmaf(W2p[9],  v9, B1); P1 = fmaf(Wdp[9],  v9, P1);
            A0 = fmaf(W1p[10], vA, A0); B0 = fmaf(W2p[10], vA, B0); P0 = fmaf(Wdp[10], vA, P0);
            A1 = fmaf(W1p[11], vB, A1); B1 = fmaf(W2p[11], vB, B1); P1 = fmaf(Wdp[11], vB, P1);

            // ---- x projection + combine ----
            float g1 = fmaf(Wx1.x, xv.x, fmaf(Wx1.y, xv.y, fmaf(Wx1.z, xv.z, fmaf(Wx1.w, xv.w, bias1))));
            float g2 = fmaf(Wx2.x, xv.x, fmaf(Wx2.y, xv.y, fmaf(Wx2.z, xv.z, fmaf(Wx2.w, xv.w, bias2))));
            g1 += A0 + A1;
            g2 += B0 + B1;

            // ---- readout of h_{t-1} (one step delayed; discarded at t==0) ----
            const float oo = fsig((P0 + P1) + bd);
            if (u == 1) s0 = oo;
            else if (u == 2) s1 = oo;
            else if (u == 3) s2 = oo;
            else {
                s3 = oo;   // u==0: completes previous quad
                if (t4 > 0 && (tid & 31) == 0)
                    *reinterpret_cast<float4*>(out + (size_t)batch * T_DIM + (t4 - 4)) =
                        make_float4(s0, s1, s2, s3);
            }

            // ---- activations + cross-gate exchange (2 independent swizzles) ----
            const float act1 = fsig(g1);                          // i (low) / f (high)
            const float act2 = fmaf(m2, fsig(m2 * g2), -m2c);     // g=tanh (low) / o (high)
            const float sw1 = swz16(act1);                        // f (low) / i (high)
            const float sw2 = swz16(act2);                        // o (low) / g (high)
            const float ig = hi ? (sw1 * sw2) : (act1 * act2);
            const float f  = hi ? act1 : sw1;
            const float o  = hi ? act2 : sw2;
            c = fmaf(f, c, ig);                                   // c = f*c + i*g
            const float tc = fmaf(2.0f, fsig(2.0f * c), -1.0f);   // tanh(c)
            h = o * tc;                                           // replicated at j and j^16

            xv = xn;
        }
    }

    // ---- tail: readout of h_{T-1} ----
    {
        float P0 = Wdp[0] * h, P1 = 0.f;
        const float v1 = dpp_f<0xB1>(h);
        const float v2 = dpp_f<0x4E>(h);
        const float v3 = dpp_f<0x1B>(h);
        const float m7 = dpp_f<0x141>(h);
        const float mF = dpp_f<0x140>(h);
        P1 = fmaf(Wdp[1], v1, P1); P0 = fmaf(Wdp[2], v2, P0); P1 = fmaf(Wdp[3], v3, P1);
        const float v6 = dpp_f<0xB1>(m7);
        const float v5 = dpp_f<0x4E>(m7);
        const float v4 = dpp_f<0x1B>(m7);
        const float m8 = dpp_f<0x141>(mF);
        P0 = fmaf(Wdp[7], m7, P0); P1 = fmaf(Wdp[6], v6, P1);
        P0 = fmaf(Wdp[5], v5, P0); P1 = fmaf(Wdp[4], v4, P1);
        const float vE = dpp_f<0xB1>(mF);
        const float vD = dpp_f<0x4E>(mF);
        const float vC = dpp_f<0x1B>(mF);
        P0 = fmaf(Wdp[15], mF, P0); P1 = fmaf(Wdp[14], vE, P1);
        P0 = fmaf(Wdp[13], vD, P0); P1 = fmaf(Wdp[12], vC, P1);
        const float v9 = dpp_f<0xB1>(m8);
        const float vA = dpp_f<0x4E>(m8);
        const float vB = dpp_f<0x1B>(m8);
        P0 = fmaf(Wdp[8],  m8, P0); P1 = fmaf(Wdp[9],  v9, P1);
        P0 = fmaf(Wdp[10], vA, P0); P1 = fmaf(Wdp[11], vB, P1);

        s3 = fsig((P0 + P1) + bd);
        if ((tid & 31) == 0)
            *reinterpret_cast<float4*>(out + (size_t)batch * T_DIM + (T_DIM - 4)) =
                make_float4(s0, s1, s2, s3);
    }
}

extern "C" void kernel_launch(void* const* d_in, const int* in_sizes, int n_in,
                              void* d_out, int out_size, void* d_ws, size_t ws_size,
                              hipStream_t stream) {
    const float* x    = (const float*)d_in[0];
    const float* W_ih = (const float*)d_in[1];
    const float* W_hh = (const float*)d_in[2];
    const float* b_ih = (const float*)d_in[3];
    const float* b_hh = (const float*)d_in[4];
    const float* W_d  = (const float*)d_in[5];
    const float* b_d  = (const float*)d_in[6];
    float* out = (float*)d_out;

    lstm_disc_kernel<<<1024, 64, 0, stream>>>(x, W_ih, W_hh, b_ih, b_hh, W_d, b_d, out);
}